// Round 10
// baseline (17.882 us; speedup 1.0000x reference)
//
#include <hip/hip_runtime.h>
#include <math.h>

#define NCLS 80
#define NANCH 3
#define NB 16
#define TGT_BLOCKS 150   // 1200 waves; 99 obj + 150 tgt = 249 blocks <= 256 CUs

__device__ __forceinline__ float softplusf(float x) {
    return fmaxf(x, 0.0f) + log1pf(expf(-fabsf(x)));
}

// Fused kernel, 512 threads/block — single scheduling round (249 blocks).
//  blocks [0, nblk_obj): objectness sweep, 8 cells/thread -> wsobj[blk]
//  blocks [nblk_obj, +TGT_BLOCKS): grid-strided target waves -> wstgt[blk][12]
__global__ void __launch_bounds__(512)
k_fused(const float* __restrict__ p0, const float* __restrict__ p1,
        const float* __restrict__ p2, int n0, int n1, int n2,
        float inv0, float inv1, float inv2,
        const float* __restrict__ targets, int T,
        const float* __restrict__ anchors,
        float* __restrict__ wsobj, int nblk_obj,
        float* __restrict__ wstgt) {
    int lane = threadIdx.x & 63, wv = threadIdx.x >> 6;

    if (blockIdx.x < (unsigned)nblk_obj) {
        // ---------------- objectness background sweep ----------------
        int total = n0 + n1 + n2;
        int base = (blockIdx.x * blockDim.x + threadIdx.x) * 8;
        float v = 0.0f;
#pragma unroll
        for (int u = 0; u < 8; ++u) {
            int idx = base + u;
            if (idx < total) {
                const float* p; int i2; float inv;
                if (idx < n0)           { p = p0; i2 = idx;           inv = inv0; }
                else if (idx < n0 + n1) { p = p1; i2 = idx - n0;      inv = inv1; }
                else                    { p = p2; i2 = idx - n0 - n1; inv = inv2; }
                v += softplusf(p[(size_t)i2 * 85 + 4]) * inv;
            }
        }
#pragma unroll
        for (int o = 32; o > 0; o >>= 1) v += __shfl_down(v, o, 64);
        __shared__ float smem[8];
        if (lane == 0) smem[wv] = v;
        __syncthreads();
        if (threadIdx.x == 0) {
            float s = 0.0f;
#pragma unroll
            for (int i = 0; i < 8; ++i) s += smem[i];
            wsobj[blockIdx.x] = s;
        }
        return;
    }

    // ---------------- matched-target waves (grid-strided entries) ----------
    // v: lv*4 + {0:cnt,1:lbox,2:lobjc,3:lcls}
    float v[12];
#pragma unroll
    for (int k = 0; k < 12; ++k) v[k] = 0.0f;

    const int perlvl = NANCH * T;
    const int nent = 3 * perlvl;                    // 1800
    const int NW = TGT_BLOCKS * 8;                  // 1200 waves
    int bt = blockIdx.x - nblk_obj;
    for (int e = bt * 8 + wv; e < nent; e += NW) {
        int yi = e / perlvl;
        int rem = e - yi * perlvl;
        int a = rem / T, ti = rem - a * T;
        const float* p = (yi == 0) ? p0 : (yi == 1) ? p1 : p2;
        int W = (yi == 0) ? 80 : (yi == 1) ? 40 : 20;
        int H = W;
        float stride = (yi == 0) ? 8.0f : (yi == 1) ? 16.0f : 32.0f;
        float Ninv = 1.0f / (float)(NB * NANCH * H * W);
        const float* tg = targets + (size_t)ti * 6;
        float tx = tg[2] * (float)W, ty = tg[3] * (float)H;
        float tw = tg[4] * (float)W, th = tg[5] * (float)H;
        float aw = anchors[yi * 6 + a * 2 + 0] / stride;
        float ah = anchors[yi * 6 + a * 2 + 1] / stride;
        float rw = tw / aw, rh = th / ah;
        float rmax = fmaxf(fmaxf(rw, 1.0f / rw), fmaxf(rh, 1.0f / rh));
        if (rmax < 4.0f) {
            int b = (int)tg[0], c = (int)tg[1];
            int ii = (int)floorf(tx), jj = (int)floorf(ty);
            int gi = min(max(ii, 0), W - 1), gj = min(max(jj, 0), H - 1);
            const float* ps = p + ((size_t)((b * NANCH + a) * H + gj) * W + gi) * 85;
            // lane-parallel class BCE: sum_j softplus(s_j) - s_c
            float cl = softplusf(ps[5 + lane]);
            if (lane < NCLS - 64) cl += softplusf(ps[5 + 64 + lane]);
            if (lane == 0) {
                v[yi * 4 + 0] += 1.0f;
                float tbx = tx - (float)ii, tby = ty - (float)jj;
                float s4 = ps[4];
                float px = 1.0f / (1.0f + expf(-ps[0]));
                float py = 1.0f / (1.0f + expf(-ps[1]));
                float pw = expf(ps[2]) * aw;
                float ph = expf(ps[3]) * ah;
                float b1x1 = px - pw * 0.5f, b1x2 = px + pw * 0.5f;
                float b1y1 = py - ph * 0.5f, b1y2 = py + ph * 0.5f;
                float b2x1 = tbx - tw * 0.5f, b2x2 = tbx + tw * 0.5f;
                float b2y1 = tby - th * 0.5f, b2y2 = tby + th * 0.5f;
                float iw = fmaxf(fminf(b1x2, b2x2) - fmaxf(b1x1, b2x1), 0.0f);
                float ih = fmaxf(fminf(b1y2, b2y2) - fmaxf(b1y1, b2y1), 0.0f);
                float inter = iw * ih;
                float uni = pw * ph + tw * th - inter + 1e-9f;
                float iou = inter / uni;
                v[yi * 4 + 1] += 1.0f - iou;
                v[yi * 4 + 2] += -s4 * fmaxf(iou, 0.0f) * Ninv;  // -x*z term
                cl -= ps[5 + c];
            }
            v[yi * 4 + 3] += cl;
        }
    }

#pragma unroll
    for (int o = 32; o > 0; o >>= 1) {
#pragma unroll
        for (int k = 0; k < 12; ++k) v[k] += __shfl_down(v[k], o, 64);
    }
    __shared__ float wsum[8][12];
    if (lane == 0) {
#pragma unroll
        for (int k = 0; k < 12; ++k) wsum[wv][k] = v[k];
    }
    __syncthreads();
    if (threadIdx.x < 12) {
        float s = 0.0f;
#pragma unroll
        for (int i = 0; i < 8; ++i) s += wsum[i][threadIdx.x];
        wstgt[(size_t)bt * 12 + threadIdx.x] = s;
    }
}

// Single-block reduction of all partials + final combine. 128 threads.
__global__ void __launch_bounds__(128)
k_final(const float* __restrict__ wstgt, int ntb,
        const float* __restrict__ wsobj, int nob,
        float* __restrict__ out) {
    int tid = threadIdx.x, lane = tid & 63, wv = tid >> 6;
    float acc[12];
#pragma unroll
    for (int k = 0; k < 12; ++k) acc[k] = 0.0f;
    for (int b = tid; b < ntb; b += 128) {
#pragma unroll
        for (int k = 0; k < 12; ++k) acc[k] += wstgt[(size_t)b * 12 + k];
    }
    float objacc = 0.0f;
    for (int b = tid; b < nob; b += 128) objacc += wsobj[b];

#pragma unroll
    for (int o = 32; o > 0; o >>= 1) {
#pragma unroll
        for (int k = 0; k < 12; ++k) acc[k] += __shfl_down(acc[k], o, 64);
        objacc += __shfl_down(objacc, o, 64);
    }
    __shared__ float smem[2][13];
    if (lane == 0) {
#pragma unroll
        for (int k = 0; k < 12; ++k) smem[wv][k] = acc[k];
        smem[wv][12] = objacc;
    }
    __syncthreads();
    if (tid == 0) {
        float tot[13];
#pragma unroll
        for (int k = 0; k < 13; ++k) tot[k] = smem[0][k] + smem[1][k];
        float res = tot[12];
#pragma unroll
        for (int lv = 0; lv < 3; ++lv) {
            float nv = fmaxf(tot[lv * 4 + 0], 1.0f);
            res += tot[lv * 4 + 1] / nv + tot[lv * 4 + 3] / (nv * (float)NCLS)
                 + tot[lv * 4 + 2];
        }
        out[0] = res;
    }
}

extern "C" void kernel_launch(void* const* d_in, const int* in_sizes, int n_in,
                              void* d_out, int out_size, void* d_ws, size_t ws_size,
                              hipStream_t stream) {
    const float* p0 = (const float*)d_in[0];
    const float* p1 = (const float*)d_in[1];
    const float* p2 = (const float*)d_in[2];
    const float* targets = (const float*)d_in[3];
    const float* anchors = (const float*)d_in[4];
    float* out = (float*)d_out;

    int n0 = in_sizes[0] / 85;
    int n1 = in_sizes[1] / 85;
    int n2 = in_sizes[2] / 85;
    int T  = in_sizes[3] / 6;

    int total = n0 + n1 + n2;
    const int THREADS = 512;
    int nblk_obj = (total + THREADS * 8 - 1) / (THREADS * 8);   // 99
    int nblk_tgt = TGT_BLOCKS;                                   // 150

    float* wstgt = (float*)d_ws;                      // nblk_tgt * 12 floats
    float* wsobj = wstgt + (size_t)nblk_tgt * 12;     // nblk_obj floats

    k_fused<<<nblk_obj + nblk_tgt, THREADS, 0, stream>>>(
        p0, p1, p2, n0, n1, n2,
        1.0f / (float)n0, 1.0f / (float)n1, 1.0f / (float)n2,
        targets, T, anchors, wsobj, nblk_obj, wstgt);

    k_final<<<1, 128, 0, stream>>>(wstgt, nblk_tgt, wsobj, nblk_obj, out);
}

// Round 11
// 17.437 us; speedup vs baseline: 1.0255x; 1.0255x over previous
//
#include <hip/hip_runtime.h>
#include <math.h>

#define NCLS 80
#define NANCH 3
#define NB 16

__device__ __forceinline__ float softplusf(float x) {
    return fmaxf(x, 0.0f) + log1pf(expf(-fabsf(x)));
}

// Fused kernel, 512 threads/block. (R9 structure — best measured: 16.97 us)
//  blocks [0, nblk_obj): objectness sweep, 8 cells/thread -> wsobj[blk]
//  blocks [nblk_obj, nblk_obj+nblk_tgt): 8 target-waves/block -> wstgt[blk][12]
__global__ void __launch_bounds__(512)
k_fused(const float* __restrict__ p0, const float* __restrict__ p1,
        const float* __restrict__ p2, int n0, int n1, int n2,
        float inv0, float inv1, float inv2,
        const float* __restrict__ targets, int T,
        const float* __restrict__ anchors,
        float* __restrict__ wsobj, int nblk_obj,
        float* __restrict__ wstgt) {
    int lane = threadIdx.x & 63, wv = threadIdx.x >> 6;

    if (blockIdx.x < (unsigned)nblk_obj) {
        // ---------------- objectness background sweep ----------------
        int total = n0 + n1 + n2;
        int base = (blockIdx.x * blockDim.x + threadIdx.x) * 8;
        float v = 0.0f;
#pragma unroll
        for (int u = 0; u < 8; ++u) {
            int idx = base + u;
            if (idx < total) {
                const float* p; int i2; float inv;
                if (idx < n0)           { p = p0; i2 = idx;           inv = inv0; }
                else if (idx < n0 + n1) { p = p1; i2 = idx - n0;      inv = inv1; }
                else                    { p = p2; i2 = idx - n0 - n1; inv = inv2; }
                v += softplusf(p[(size_t)i2 * 85 + 4]) * inv;
            }
        }
#pragma unroll
        for (int o = 32; o > 0; o >>= 1) v += __shfl_down(v, o, 64);
        __shared__ float smem[8];
        if (lane == 0) smem[wv] = v;
        __syncthreads();
        if (threadIdx.x == 0) {
            float s = 0.0f;
#pragma unroll
            for (int i = 0; i < 8; ++i) s += smem[i];
            wsobj[blockIdx.x] = s;
        }
        return;
    }

    // ---------------- matched-target waves ----------------
    int bt = blockIdx.x - nblk_obj;
    int w = bt * 8 + wv;                 // global wave id = (lvl,anchor,tgt)
    int perlvl = NANCH * T;
    int nwaves = 3 * perlvl;
    float cnt = 0.0f, lbox = 0.0f, lobjc = 0.0f, lcls = 0.0f;
    int yi = 0;
    if (w < nwaves) {
        yi = w / perlvl;
        int e = w - yi * perlvl;
        int a = e / T, ti = e - a * T;
        const float* p = (yi == 0) ? p0 : (yi == 1) ? p1 : p2;
        int W = (yi == 0) ? 80 : (yi == 1) ? 40 : 20;
        int H = W;
        float stride = (yi == 0) ? 8.0f : (yi == 1) ? 16.0f : 32.0f;
        float Ninv = 1.0f / (float)(NB * NANCH * H * W);
        const float* tg = targets + (size_t)ti * 6;
        float tx = tg[2] * (float)W, ty = tg[3] * (float)H;
        float tw = tg[4] * (float)W, th = tg[5] * (float)H;
        float aw = anchors[yi * 6 + a * 2 + 0] / stride;
        float ah = anchors[yi * 6 + a * 2 + 1] / stride;
        float rw = tw / aw, rh = th / ah;
        float rmax = fmaxf(fmaxf(rw, 1.0f / rw), fmaxf(rh, 1.0f / rh));
        if (rmax < 4.0f) {
            int b = (int)tg[0], c = (int)tg[1];
            int ii = (int)floorf(tx), jj = (int)floorf(ty);
            int gi = min(max(ii, 0), W - 1), gj = min(max(jj, 0), H - 1);
            const float* ps = p + ((size_t)((b * NANCH + a) * H + gj) * W + gi) * 85;
            // lane-parallel class BCE: sum_j softplus(s_j) - s_c
            float cl = softplusf(ps[5 + lane]);
            if (lane < NCLS - 64) cl += softplusf(ps[5 + 64 + lane]);
            if (lane == 0) {
                cnt = 1.0f;
                float tbx = tx - (float)ii, tby = ty - (float)jj;
                float s4 = ps[4];
                float px = 1.0f / (1.0f + expf(-ps[0]));
                float py = 1.0f / (1.0f + expf(-ps[1]));
                float pw = expf(ps[2]) * aw;
                float ph = expf(ps[3]) * ah;
                float b1x1 = px - pw * 0.5f, b1x2 = px + pw * 0.5f;
                float b1y1 = py - ph * 0.5f, b1y2 = py + ph * 0.5f;
                float b2x1 = tbx - tw * 0.5f, b2x2 = tbx + tw * 0.5f;
                float b2y1 = tby - th * 0.5f, b2y2 = tby + th * 0.5f;
                float iw = fmaxf(fminf(b1x2, b2x2) - fmaxf(b1x1, b2x1), 0.0f);
                float ih = fmaxf(fminf(b1y2, b2y2) - fmaxf(b1y1, b2y1), 0.0f);
                float inter = iw * ih;
                float uni = pw * ph + tw * th - inter + 1e-9f;
                float iou = inter / uni;
                lbox = 1.0f - iou;
                lobjc = -s4 * fmaxf(iou, 0.0f) * Ninv;  // bce(x,z)-bce(x,0)
                cl -= ps[5 + c];
            }
            lcls = cl;
        }
    }
#pragma unroll
    for (int o = 32; o > 0; o >>= 1) lcls += __shfl_down(lcls, o, 64);

    __shared__ float wsum[8][4];
    __shared__ int wlvl[8];
    if (lane == 0) {
        wsum[wv][0] = cnt; wsum[wv][1] = lbox; wsum[wv][2] = lobjc; wsum[wv][3] = lcls;
        wlvl[wv] = yi;
    }
    __syncthreads();
    if (threadIdx.x < 12) {
        int lv = threadIdx.x >> 2, k = threadIdx.x & 3;
        float s = 0.0f;
#pragma unroll
        for (int i = 0; i < 8; ++i)
            if (wlvl[i] == lv) s += wsum[i][k];
        wstgt[(size_t)bt * 12 + threadIdx.x] = s;
    }
}

// Single-block reduction of all partials + final combine. 128 threads.
__global__ void __launch_bounds__(128)
k_final(const float* __restrict__ wstgt, int ntb,
        const float* __restrict__ wsobj, int nob,
        float* __restrict__ out) {
    int tid = threadIdx.x, lane = tid & 63, wv = tid >> 6;
    float acc[12];
#pragma unroll
    for (int k = 0; k < 12; ++k) acc[k] = 0.0f;
    for (int b = tid; b < ntb; b += 128) {
#pragma unroll
        for (int k = 0; k < 12; ++k) acc[k] += wstgt[(size_t)b * 12 + k];
    }
    float objacc = 0.0f;
    for (int b = tid; b < nob; b += 128) objacc += wsobj[b];

#pragma unroll
    for (int o = 32; o > 0; o >>= 1) {
#pragma unroll
        for (int k = 0; k < 12; ++k) acc[k] += __shfl_down(acc[k], o, 64);
        objacc += __shfl_down(objacc, o, 64);
    }
    __shared__ float smem[2][13];
    if (lane == 0) {
#pragma unroll
        for (int k = 0; k < 12; ++k) smem[wv][k] = acc[k];
        smem[wv][12] = objacc;
    }
    __syncthreads();
    if (tid == 0) {
        float tot[13];
#pragma unroll
        for (int k = 0; k < 13; ++k) tot[k] = smem[0][k] + smem[1][k];
        float res = tot[12];
#pragma unroll
        for (int lv = 0; lv < 3; ++lv) {
            float nv = fmaxf(tot[lv * 4 + 0], 1.0f);
            res += tot[lv * 4 + 1] / nv + tot[lv * 4 + 3] / (nv * (float)NCLS)
                 + tot[lv * 4 + 2];
        }
        out[0] = res;
    }
}

extern "C" void kernel_launch(void* const* d_in, const int* in_sizes, int n_in,
                              void* d_out, int out_size, void* d_ws, size_t ws_size,
                              hipStream_t stream) {
    const float* p0 = (const float*)d_in[0];
    const float* p1 = (const float*)d_in[1];
    const float* p2 = (const float*)d_in[2];
    const float* targets = (const float*)d_in[3];
    const float* anchors = (const float*)d_in[4];
    float* out = (float*)d_out;

    int n0 = in_sizes[0] / 85;
    int n1 = in_sizes[1] / 85;
    int n2 = in_sizes[2] / 85;
    int T  = in_sizes[3] / 6;

    int total = n0 + n1 + n2;
    const int THREADS = 512;
    int nblk_obj = (total + THREADS * 8 - 1) / (THREADS * 8);   // 8 cells/thread
    int nwaves = 3 * NANCH * T;
    int nblk_tgt = (nwaves + 7) / 8;                            // 8 waves/block

    float* wstgt = (float*)d_ws;                      // nblk_tgt * 12 floats
    float* wsobj = wstgt + (size_t)nblk_tgt * 12;     // nblk_obj floats

    k_fused<<<nblk_obj + nblk_tgt, THREADS, 0, stream>>>(
        p0, p1, p2, n0, n1, n2,
        1.0f / (float)n0, 1.0f / (float)n1, 1.0f / (float)n2,
        targets, T, anchors, wsobj, nblk_obj, wstgt);

    k_final<<<1, 128, 0, stream>>>(wstgt, nblk_tgt, wsobj, nblk_obj, out);
}